// Round 6
// baseline (86.223 us; speedup 1.0000x reference)
//
#include <hip/hip_runtime.h>

// Laplacian pyramid loss via linearity: pyr(p) - pyr(t) = pyr(p - t).
// R6: cross-tile software pipeline. Grid-stride over tiles; while computing
// tile k (LDS phases), tile k+1's global loads are in flight in a 2nd register
// set. Barriers = explicit "s_waitcnt lgkmcnt(0)" + s_barrier (no vmcnt drain,
// so prefetch survives barriers — T14/8-phase pattern). Levels 2+3+4 fused
// into one per-image LDS-resident kernel (512 thr, ~115 KB LDS).

__device__ __forceinline__ int reflect_i(int m, int S) {
    if (m < 0) m = -m;
    if (m >= S) m = 2 * S - 2 - m;
    return m;
}

__device__ __forceinline__ void wg_barrier() {
    asm volatile("s_waitcnt lgkmcnt(0)" ::: "memory");
    __builtin_amdgcn_s_barrier();
}

// cur tile: rows ty0-4 .. ty0+TH+2 (RC=TH+7), cols tx0-8 .. tx0+TW+7 (WC=TW+16)
// down tile + halo: rows yd0-1 .. yd0+TH/2, cols xd0-1 .. xd0+TW/2
template <int TW, int TH, int L0>
__global__ __launch_bounds__(256, 4)
void fused_kernel(const float* __restrict__ a, const float* __restrict__ b,
                  float* __restrict__ dwn, float* __restrict__ acc,
                  int S, float scale, int ntiles) {
    const int D = S >> 1;
    const int nx = S / TW, ny = S / TH;
    constexpr int RC = TH + 7;
    constexpr int WC = TW + 16;
    constexpr int C4 = WC / 4;
    constexpr int CH = TW / 2 + 2;
    constexpr int RD = TH / 2 + 2;
    constexpr int HS = CH + 2;
    constexpr int TOT = RC * C4;
    constexpr int UN = (TOT + 255) / 256;

    __shared__ float Lc[RC][WC];
    __shared__ float Lh[RC][HS];
    __shared__ float Ld[RD][HS];
    __shared__ float sred[4];

    const int tid = threadIdx.x;
    const int stride = gridDim.x;

    auto load_tile = [&](int tile, float4* va, float4* vb, unsigned& okm) {
        int bx = tile % nx, by = (tile / nx) % ny, n = tile / (nx * ny);
        int tx0 = bx * TW, ty0 = by * TH;
        size_t base = (size_t)n * S * S;
        okm = 0u;
        #pragma unroll
        for (int u = 0; u < UN; u++) {
            int i = tid + 256 * u;
            int r = i / C4, q = i % C4;
            int gc = tx0 - 8 + 4 * q;
            bool ok = (i < TOT) && (gc >= 0) && (gc <= S - 4);
            if (ok) {
                okm |= (1u << u);
                int gy = reflect_i(ty0 - 4 + r, S);
                va[u] = *(const float4*)(a + base + (size_t)gy * S + gc);
                if constexpr (L0)
                    vb[u] = *(const float4*)(b + base + (size_t)gy * S + gc);
            }
        }
    };

    auto stage = [&](int tile, const float4* va, const float4* vb, unsigned okm) {
        int bx = tile % nx;
        int tx0 = bx * TW;
        #pragma unroll
        for (int u = 0; u < UN; u++) {
            if (okm & (1u << u)) {
                int i = tid + 256 * u;
                int r = i / C4, q = i % C4;
                float4 v = va[u];
                if constexpr (L0) {
                    v.x -= vb[u].x; v.y -= vb[u].y; v.z -= vb[u].z; v.w -= vb[u].w;
                }
                *(float4*)&Lc[r][4 * q] = v;
            }
        }
        wg_barrier();
        if (tx0 == 0) {
            for (int i = tid; i < RC * 4; i += 256) {
                int r = i >> 2, j = i & 3;
                Lc[r][4 + j] = Lc[r][12 - j];          // col -4+j <- col 4-j
            }
        }
        if (tx0 + TW == S) {
            for (int i = tid; i < RC * 3; i += 256) {
                int r = i / 3, k = i % 3;
                Lc[r][TW + 8 + k] = Lc[r][TW + 6 - k]; // col S+k <- col S-2-k
            }
        }
        if (tx0 == 0 || tx0 + TW == S) wg_barrier();
    };

    auto compute = [&](int tile) {
        int bx = tile % nx, by = (tile / nx) % ny, n = tile / (nx * ny);
        int tx0 = bx * TW, ty0 = by * TH;
        int xd0 = tx0 >> 1, yd0 = ty0 >> 1;

        // phase 2: horizontal 5-tap at down col xd0-1+xh
        for (int i = tid; i < RC * CH; i += 256) {
            int r = i / CH, xh = i % CH;
            int c = 2 * xh + 4;
            Lh[r][xh] = Lc[r][c] + 4.f * Lc[r][c + 1] + 6.f * Lc[r][c + 2]
                      + 4.f * Lc[r][c + 3] + Lc[r][c + 4];
        }
        wg_barrier();

        // phase 3: vertical 5-tap -> down tile (halo included)
        for (int i = tid; i < RD * CH; i += 256) {
            int yh = i / CH, xh = i % CH;
            int r = 2 * yh;
            Ld[yh][xh] = (Lh[r][xh] + 4.f * Lh[r + 1][xh] + 6.f * Lh[r + 2][xh]
                        + 4.f * Lh[r + 3][xh] + Lh[r + 4][xh]) * (1.f / 256.f);
        }
        wg_barrier();

        // phase 3b: write interior down to global (next level's input)
        {
            size_t dbase = (size_t)n * D * D;
            constexpr int CW4 = TW / 8;
            for (int i = tid; i < (TH / 2) * CW4; i += 256) {
                int rr = i / CW4, k = i % CW4;
                float4 o4;
                o4.x = Ld[1 + rr][1 + 4 * k];
                o4.y = Ld[1 + rr][2 + 4 * k];
                o4.z = Ld[1 + rr][3 + 4 * k];
                o4.w = Ld[1 + rr][4 + 4 * k];
                *(float4*)(dwn + dbase + (size_t)(yd0 + rr) * D + xd0 + 4 * k) = o4;
            }
        }

        // phase 4: up + |cur - up| on 2x2 quads (shared 3x3 down taps)
        float sum = 0.f;
        for (int i = tid; i < (TH / 2) * (TW / 2); i += 256) {
            int yh2 = i / (TW / 2), q = i % (TW / 2);
            float A00 = Ld[yh2][q],     A01 = Ld[yh2][q + 1],     A02 = Ld[yh2][q + 2];
            float A10 = Ld[yh2 + 1][q], A11 = Ld[yh2 + 1][q + 1], A12 = Ld[yh2 + 1][q + 2];
            float A20 = Ld[yh2 + 2][q], A21 = Ld[yh2 + 2][q + 1], A22 = Ld[yh2 + 2][q + 2];
            float ex0 = (A00 + 6.f * A01 + A02) * 0.125f;
            float ex1 = (A10 + 6.f * A11 + A12) * 0.125f;
            float ex2 = (A20 + 6.f * A21 + A22) * 0.125f;
            float ox0 = (A01 + A02) * 0.5f;
            float ox1 = (A11 + A12) * 0.5f;
            float ox2 = (A21 + A22) * 0.5f;
            float uee = (ex0 + 6.f * ex1 + ex2) * 0.125f;
            float ueo = (ox0 + 6.f * ox1 + ox2) * 0.125f;
            float uoe = (ex1 + ex2) * 0.5f;
            float uoo = (ox1 + ox2) * 0.5f;
            int ry = 2 * yh2 + 4, cx = 2 * q + 8;
            sum += fabsf(Lc[ry][cx] - uee) + fabsf(Lc[ry][cx + 1] - ueo)
                 + fabsf(Lc[ry + 1][cx] - uoe) + fabsf(Lc[ry + 1][cx + 1] - uoo);
        }
        #pragma unroll
        for (int o = 32; o > 0; o >>= 1) sum += __shfl_down(sum, o, 64);
        int lane = tid & 63, w = tid >> 6;
        if (lane == 0) sred[w] = sum;
        wg_barrier();
        if (tid == 0)
            atomicAdd(&acc[tile & 63], (sred[0] + sred[1] + sred[2] + sred[3]) * scale);
    };

    int t = blockIdx.x;
    if (t >= ntiles) return;
    float4 va0[UN], vb0[UN], va1[UN], vb1[UN];
    unsigned ok0, ok1;
    load_tile(t, va0, vb0, ok0);
    while (true) {
        int t2 = t + stride;
        stage(t, va0, vb0, ok0);
        if (t2 < ntiles) load_tile(t2, va1, vb1, ok1);   // in flight during compute
        compute(t);
        if (t2 >= ntiles) break;
        int t3 = t2 + stride;
        stage(t2, va1, vb1, ok1);
        if (t3 < ntiles) load_tile(t3, va0, vb0, ok0);
        compute(t2);
        if (t3 >= ntiles) break;
        t = t3;
    }
}

// ---- in-LDS level: cur (SxS resident) -> dn (DxD); returns per-thread
// partial sum of |cur - up(dn)|. Reflect = plain index math.
__device__ float level_in_lds(const float* cur, float* h, float* dn,
                              int S, int tid, int nt) {
    const int D = S >> 1;
    for (int i = tid; i < S * D; i += nt) {
        int r = i / D, xh = i % D;
        int c0 = reflect_i(2 * xh - 2, S), c1 = reflect_i(2 * xh - 1, S);
        int c3 = 2 * xh + 1, c4 = reflect_i(2 * xh + 2, S);
        const float* row = cur + r * S;
        h[i] = row[c0] + 4.f * row[c1] + 6.f * row[2 * xh] + 4.f * row[c3] + row[c4];
    }
    wg_barrier();
    for (int i = tid; i < D * D; i += nt) {
        int yh = i / D, xh = i % D;
        int r0 = reflect_i(2 * yh - 2, S), r1 = reflect_i(2 * yh - 1, S);
        int r3 = 2 * yh + 1, r4 = reflect_i(2 * yh + 2, S);
        dn[i] = (h[r0 * D + xh] + 4.f * h[r1 * D + xh] + 6.f * h[2 * yh * D + xh]
               + 4.f * h[r3 * D + xh] + h[r4 * D + xh]) * (1.f / 256.f);
    }
    wg_barrier();
    float sum = 0.f;
    for (int i = tid; i < D * D; i += nt) {
        int yh2 = i / D, q = i % D;
        int rm = (yh2 == 0) ? 1 : yh2 - 1;
        int rp = (yh2 == D - 1) ? D - 1 : yh2 + 1;
        int cm = (q == 0) ? 1 : q - 1;
        int cp = (q == D - 1) ? D - 1 : q + 1;
        float A00 = dn[rm * D + cm], A01 = dn[rm * D + q], A02 = dn[rm * D + cp];
        float A10 = dn[yh2 * D + cm], A11 = dn[yh2 * D + q], A12 = dn[yh2 * D + cp];
        float A20 = dn[rp * D + cm], A21 = dn[rp * D + q], A22 = dn[rp * D + cp];
        float ex0 = (A00 + 6.f * A01 + A02) * 0.125f;
        float ex1 = (A10 + 6.f * A11 + A12) * 0.125f;
        float ex2 = (A20 + 6.f * A21 + A22) * 0.125f;
        float ox0 = (A01 + A02) * 0.5f;
        float ox1 = (A11 + A12) * 0.5f;
        float ox2 = (A21 + A22) * 0.5f;
        float uee = (ex0 + 6.f * ex1 + ex2) * 0.125f;
        float ueo = (ox0 + 6.f * ox1 + ox2) * 0.125f;
        float uoe = (ex1 + ex2) * 0.5f;
        float uoo = (ox1 + ox2) * 0.5f;
        const float* c0 = cur + (2 * yh2) * S + 2 * q;
        sum += fabsf(c0[0] - uee) + fabsf(c0[1] - ueo)
             + fabsf(c0[S] - uoe) + fabsf(c0[S + 1] - uoo);
    }
    wg_barrier();
    return sum;
}

// levels 2+3+4 for one image per block: down1 (128x128) -> all in LDS.
__global__ __launch_bounds__(512, 1)
void tail_kernel(const float* __restrict__ d1, float* __restrict__ acc,
                 float s2, float s3, float s4) {
    __shared__ float cur[128 * 128];   // 64 KB; later reused for dn3, dn4
    __shared__ float hbuf[128 * 64];   // 32 KB; reused per level
    __shared__ float dn2[64 * 64];     // 16 KB
    int n = blockIdx.x, tid = threadIdx.x;
    const int nt = 512;
    const float4* src = (const float4*)(d1 + (size_t)n * 128 * 128);
    for (int i = tid; i < 128 * 32; i += nt) ((float4*)cur)[i] = src[i];
    wg_barrier();
    float sum = level_in_lds(cur, hbuf, dn2, 128, tid, nt) * s2;
    float* dn3 = cur;                  // 32*32, cur data now dead
    sum += level_in_lds(dn2, hbuf, dn3, 64, tid, nt) * s3;
    float* dn4 = cur + 32 * 32;        // 16*16
    sum += level_in_lds(dn3, hbuf, dn4, 32, tid, nt) * s4;
    #pragma unroll
    for (int o = 32; o > 0; o >>= 1) sum += __shfl_down(sum, o, 64);
    __shared__ float s[8];
    int lane = tid & 63, w = tid >> 6;
    if (lane == 0) s[w] = sum;
    wg_barrier();
    if (tid == 0) {
        float v = 0.f;
        #pragma unroll
        for (int i = 0; i < 8; i++) v += s[i];
        atomicAdd(&acc[n & 63], v);
    }
}

__global__ void finish_kernel(const float* __restrict__ acc, float* __restrict__ out) {
    float v = acc[threadIdx.x];
    #pragma unroll
    for (int o = 32; o > 0; o >>= 1) v += __shfl_down(v, o, 64);
    if (threadIdx.x == 0) out[0] = v;
}

extern "C" void kernel_launch(void* const* d_in, const int* in_sizes, int n_in,
                              void* d_out, int out_size, void* d_ws, size_t ws_size,
                              hipStream_t stream) {
    const float* p = (const float*)d_in[0];
    const float* t = (const float*)d_in[1];
    float* out = (float*)d_out;
    float* acc = (float*)d_ws;          // 64 accumulator slots
    float* dn0 = acc + 64;              // 48 * 256 * 256
    float* dn1 = dn0 + (size_t)48 * 256 * 256;  // 48 * 128 * 128

    hipMemsetAsync(acc, 0, 64 * sizeof(float), stream);

    const int N = 48;  // 16 batch * 3 channels (depthwise)

    // level 0: S=512, tiles 64x32 -> 6144 tiles on 1024 blocks (6/block)
    {
        int ntiles = N * (512 / 64) * (512 / 32);
        float scale = 1.f / (float)(N * 512 * 512);
        fused_kernel<64, 32, 1><<<1024, 256, 0, stream>>>(p, t, dn0, acc, 512, scale, ntiles);
    }
    // level 1: S=256 -> 1536 tiles on 512 blocks (3/block)
    {
        int ntiles = N * (256 / 64) * (256 / 32);
        float scale = 2.f / (float)(N * 256 * 256);
        fused_kernel<64, 32, 0><<<512, 256, 0, stream>>>(dn0, nullptr, dn1, acc, 256, scale, ntiles);
    }
    // levels 2+3+4: one block per image, fully LDS-resident
    tail_kernel<<<N, 512, 0, stream>>>(dn1, acc,
                                       4.f / (float)(N * 128 * 128),
                                       8.f / (float)(N * 64 * 64),
                                       16.f / (float)(N * 32 * 32));
    finish_kernel<<<1, 64, 0, stream>>>(acc, out);
}

// Round 7
// 78.364 us; speedup vs baseline: 1.1003x; 1.1003x over previous
//
#include <hip/hip_runtime.h>

// Laplacian pyramid loss via linearity: pyr(p) - pyr(t) = pyr(p - t).
// R7: barrier-free WAVE-STREAMING for L0/L1. One wave = 64 down-cols x DH
// down-rows strip. Lane j owns down col DB+j (cur cols 2dc,2dc+1, float2).
// Everything in registers: h = 5-tap via 3 shuffles/row; v-tap via rolling
// 5-row h window; up-interp via rolling ex/ox rows (2 shuffles per down row);
// lap emitted 2 cur rows at a time from a rolling cur buffer. No LDS, no
// barriers -> thousands of independent waves (R6 was barrier/latency-bound
// at 20% VALU with L3-resident data). Col strips overlap 2 halo lanes;
// ownership masks gate stores and the |.| sum. Image-edge reflect = lane-
// local selects (h: 6c0+8c1+2c2 left, +7cx right; up: dl:=dr / dr:=d).
// Tail (L2-4, per-image LDS pyramid) and finish kept from R6 (proven).

__device__ __forceinline__ int reflect_i(int m, int S) {
    if (m < 0) m = -m;
    if (m >= S) m = 2 * S - 2 - m;
    return m;
}

__device__ __forceinline__ void wg_barrier() {
    asm volatile("s_waitcnt lgkmcnt(0)" ::: "memory");
    __builtin_amdgcn_s_barrier();
}

template <int SZ, int ISL0, int DH, int NCS, int NRS>
__global__ __launch_bounds__(256)
void stream_kernel(const float* __restrict__ a, const float* __restrict__ b,
                   float* __restrict__ dwn, float* __restrict__ acc, float scale) {
    constexpr int S = SZ, D = SZ / 2;
    const int wid  = (blockIdx.x * 256 + threadIdx.x) >> 6;
    const int lane = threadIdx.x & 63;
    const int cs = wid % NCS;
    const int rs = (wid / NCS) % NRS;
    const int n  = wid / (NCS * NRS);

    int DB, relS, relE;
    if constexpr (SZ == 512) {
        DB   = cs == 0 ? 0 : cs == 1 ? 59 : cs == 2 ? 119 : cs == 3 ? 179 : 192;
        relS = cs == 0 ? 0 : cs == 4 ? 49 : 2;
        relE = cs == 4 ? 63 : cs == 0 ? 60 : 61;
    } else {
        DB   = cs == 0 ? 0 : cs == 1 ? 59 : 64;
        relS = cs == 0 ? 0 : cs == 1 ? 2 : 57;
        relE = cs == 0 ? 60 : cs == 1 ? 61 : 63;
    }

    const bool leftE  = (DB == 0);
    const bool rightE = (DB + 63 == D - 1);
    const int dc = DB + lane;
    const bool ownL = (lane >= relS) && (lane <= relE);

    const float* pa = a + (size_t)n * S * S + 2 * dc;
    const float* pb = ISL0 ? (b + (size_t)n * S * S + 2 * dc) : nullptr;

    auto loadrow = [&](int r, float2& c) {
        int gr = reflect_i(r, S);
        c = *(const float2*)(pa + (size_t)gr * S);
        if constexpr (ISL0) {
            float2 u = *(const float2*)(pb + (size_t)gr * S);
            c.x -= u.x; c.y -= u.y;
        }
    };
    auto hof = [&](float2 c) -> float {
        float cLx = __shfl_up(c.x, 1, 64);
        float cLy = __shfl_up(c.y, 1, 64);
        float cRx = __shfl_down(c.x, 1, 64);
        float h = cLx + 4.f * cLy + 6.f * c.x + 4.f * c.y + cRx;
        if (leftE && lane == 0)   h = 6.f * c.x + 8.f * c.y + 2.f * cRx;
        if (rightE && lane == 63) h = cLx + 4.f * cLy + 7.f * c.x + 4.f * c.y;
        return h;
    };

    const int R0 = rs * DH, R1 = R0 + DH - 1;
    float2 cA, cB, cC, cD, cE;
    float hA, hB, hC, hD, hE;
    const int rbase = 2 * R0 - 4;           // row of cA at m = R0-1
    loadrow(rbase + 0, cA); loadrow(rbase + 1, cB); loadrow(rbase + 2, cC);
    loadrow(rbase + 3, cD); loadrow(rbase + 4, cE);
    hA = hof(cA); hB = hof(cB); hC = hof(cC); hD = hof(cD); hE = hof(cE);

    float ex0 = 0.f, ex1 = 0.f, ox0 = 0.f, ox1 = 0.f;
    float sum = 0.f;
    float* dptr = dwn + (size_t)n * D * D + dc;

    for (int it = 0; it < DH + 2; ++it) {
        const int m = R0 - 1 + it;
        // down row m  <- cur rows 2m-2..2m+2 (h window), /256
        float d = (hA + 4.f * hB + 6.f * hC + 4.f * hD + hE) * (1.f / 256.f);
        float dl = __shfl_up(d, 1, 64);
        float dr = __shfl_down(d, 1, 64);
        if (leftE && lane == 0)   dl = dr;   // down col -1 -> 1
        if (rightE && lane == 63) dr = d;    // down col D  -> D-1
        float ex2 = 0.125f * (dl + 6.f * d + dr);  // up at even cur col 2dc
        float ox2 = 0.5f  * (d + dr);              // up at odd  cur col 2dc+1

        if (it >= 1 && it <= DH && ownL)     // m in [R0..R1]
            dptr[(size_t)m * D] = d;

        if (it >= 2) {                        // emit lap rows 2me, 2me+1
            const int me = m - 1;
            float eA = (me == 0) ? ex2 : ex0;         // down row -1 -> 1
            float oA = (me == 0) ? ox2 : ox0;
            float eC = (me == D - 1) ? ex1 : ex2;     // down row D -> D-1
            float oC = (me == D - 1) ? ox1 : ox2;
            float uee = 0.125f * (eA + 6.f * ex1 + eC);
            float ueo = 0.125f * (oA + 6.f * ox1 + oC);
            float uoe = 0.5f * (ex1 + eC);
            float uoo = 0.5f * (ox1 + oC);
            if (ownL)
                sum += fabsf(cA.x - uee) + fabsf(cA.y - ueo)
                     + fabsf(cB.x - uoe) + fabsf(cB.y - uoo);
        }
        ex0 = ex1; ex1 = ex2; ox0 = ox1; ox1 = ox2;
        cA = cC; cB = cD; cC = cE;
        hA = hC; hB = hD; hC = hE;
        if (it < DH + 1) {
            loadrow(2 * m + 3, cD); hD = hof(cD);
            loadrow(2 * m + 4, cE); hE = hof(cE);
        }
    }

    #pragma unroll
    for (int o = 32; o > 0; o >>= 1) sum += __shfl_down(sum, o, 64);
    if (lane == 0) atomicAdd(&acc[wid & 63], sum * scale);
}

// ---- in-LDS level (tail): cur (SxS resident) -> dn (DxD); returns partial
// sum of |cur - up(dn)|. Reflect = plain index math.
__device__ float level_in_lds(const float* cur, float* h, float* dn,
                              int S, int tid, int nt) {
    const int D = S >> 1;
    for (int i = tid; i < S * D; i += nt) {
        int r = i / D, xh = i % D;
        int c0 = reflect_i(2 * xh - 2, S), c1 = reflect_i(2 * xh - 1, S);
        int c3 = 2 * xh + 1, c4 = reflect_i(2 * xh + 2, S);
        const float* row = cur + r * S;
        h[i] = row[c0] + 4.f * row[c1] + 6.f * row[2 * xh] + 4.f * row[c3] + row[c4];
    }
    wg_barrier();
    for (int i = tid; i < D * D; i += nt) {
        int yh = i / D, xh = i % D;
        int r0 = reflect_i(2 * yh - 2, S), r1 = reflect_i(2 * yh - 1, S);
        int r3 = 2 * yh + 1, r4 = reflect_i(2 * yh + 2, S);
        dn[i] = (h[r0 * D + xh] + 4.f * h[r1 * D + xh] + 6.f * h[2 * yh * D + xh]
               + 4.f * h[r3 * D + xh] + h[r4 * D + xh]) * (1.f / 256.f);
    }
    wg_barrier();
    float sum = 0.f;
    for (int i = tid; i < D * D; i += nt) {
        int yh2 = i / D, q = i % D;
        int rm = (yh2 == 0) ? 1 : yh2 - 1;
        int rp = (yh2 == D - 1) ? D - 1 : yh2 + 1;
        int cm = (q == 0) ? 1 : q - 1;
        int cp = (q == D - 1) ? D - 1 : q + 1;
        float A00 = dn[rm * D + cm], A01 = dn[rm * D + q], A02 = dn[rm * D + cp];
        float A10 = dn[yh2 * D + cm], A11 = dn[yh2 * D + q], A12 = dn[yh2 * D + cp];
        float A20 = dn[rp * D + cm], A21 = dn[rp * D + q], A22 = dn[rp * D + cp];
        float ex0 = (A00 + 6.f * A01 + A02) * 0.125f;
        float ex1 = (A10 + 6.f * A11 + A12) * 0.125f;
        float ex2 = (A20 + 6.f * A21 + A22) * 0.125f;
        float ox0 = (A01 + A02) * 0.5f;
        float ox1 = (A11 + A12) * 0.5f;
        float ox2 = (A21 + A22) * 0.5f;
        float uee = (ex0 + 6.f * ex1 + ex2) * 0.125f;
        float ueo = (ox0 + 6.f * ox1 + ox2) * 0.125f;
        float uoe = (ex1 + ex2) * 0.5f;
        float uoo = (ox1 + ox2) * 0.5f;
        const float* c0 = cur + (2 * yh2) * S + 2 * q;
        sum += fabsf(c0[0] - uee) + fabsf(c0[1] - ueo)
             + fabsf(c0[S] - uoe) + fabsf(c0[S + 1] - uoo);
    }
    wg_barrier();
    return sum;
}

// levels 2+3+4 for one image per block: down1 (128x128) -> all in LDS.
__global__ __launch_bounds__(512, 1)
void tail_kernel(const float* __restrict__ d1, float* __restrict__ acc,
                 float s2, float s3, float s4) {
    __shared__ float cur[128 * 128];   // 64 KB; later reused for dn3, dn4
    __shared__ float hbuf[128 * 64];   // 32 KB; reused per level
    __shared__ float dn2[64 * 64];     // 16 KB
    int n = blockIdx.x, tid = threadIdx.x;
    const int nt = 512;
    const float4* src = (const float4*)(d1 + (size_t)n * 128 * 128);
    for (int i = tid; i < 128 * 32; i += nt) ((float4*)cur)[i] = src[i];
    wg_barrier();
    float sum = level_in_lds(cur, hbuf, dn2, 128, tid, nt) * s2;
    float* dn3 = cur;                  // 32*32, cur data now dead
    sum += level_in_lds(dn2, hbuf, dn3, 64, tid, nt) * s3;
    float* dn4 = cur + 32 * 32;        // 16*16
    sum += level_in_lds(dn3, hbuf, dn4, 32, tid, nt) * s4;
    #pragma unroll
    for (int o = 32; o > 0; o >>= 1) sum += __shfl_down(sum, o, 64);
    __shared__ float s[8];
    int lane = tid & 63, w = tid >> 6;
    if (lane == 0) s[w] = sum;
    wg_barrier();
    if (tid == 0) {
        float v = 0.f;
        #pragma unroll
        for (int i = 0; i < 8; i++) v += s[i];
        atomicAdd(&acc[n & 63], v);
    }
}

__global__ void finish_kernel(const float* __restrict__ acc, float* __restrict__ out) {
    float v = acc[threadIdx.x];
    #pragma unroll
    for (int o = 32; o > 0; o >>= 1) v += __shfl_down(v, o, 64);
    if (threadIdx.x == 0) out[0] = v;
}

extern "C" void kernel_launch(void* const* d_in, const int* in_sizes, int n_in,
                              void* d_out, int out_size, void* d_ws, size_t ws_size,
                              hipStream_t stream) {
    const float* p = (const float*)d_in[0];
    const float* t = (const float*)d_in[1];
    float* out = (float*)d_out;
    float* acc = (float*)d_ws;                    // 64 accumulator slots
    float* dn0 = acc + 64;                        // 48 * 256 * 256
    float* dn1 = dn0 + (size_t)48 * 256 * 256;    // 48 * 128 * 128

    hipMemsetAsync(acc, 0, 64 * sizeof(float), stream);

    const int N = 48;  // 16 batch * 3 channels (depthwise)

    // L0: S=512, D=256: 5 col strips x 16 row strips x 48 imgs = 3840 waves
    {
        float scale = 1.f / (float)(N * 512 * 512);
        stream_kernel<512, 1, 16, 5, 16><<<960, 256, 0, stream>>>(p, t, dn0, acc, scale);
    }
    // L1: S=256, D=128: 3 col strips x 8 row strips x 48 = 1152 waves
    {
        float scale = 2.f / (float)(N * 256 * 256);
        stream_kernel<256, 0, 16, 3, 8><<<288, 256, 0, stream>>>(dn0, nullptr, dn1, acc, scale);
    }
    // levels 2+3+4: one block per image, fully LDS-resident
    tail_kernel<<<N, 512, 0, stream>>>(dn1, acc,
                                       4.f / (float)(N * 128 * 128),
                                       8.f / (float)(N * 64 * 64),
                                       16.f / (float)(N * 32 * 32));
    finish_kernel<<<1, 64, 0, stream>>>(acc, out);
}